// Round 6
// baseline (33.174 us; speedup 1.0000x reference)
//
#include <hip/hip_runtime.h>

// ============================================================================
// ROUND 6 PROBE: identical R5 kernel, enqueued TWICE in the timed graph.
// Purpose: separate fixed graph-replay overhead from true kernel exec time.
//   exec = dur(2x) - dur(1x) = dur(2x) - 19.2us.
// Second launch is idempotent (same inputs -> same outputs), so correctness
// and determinism are unaffected. Next round reverts to a single launch.
// ============================================================================

#define NN 1024
#define DD 64
#define NF 11
#define TI 16
#define BT 1024

__global__ __launch_bounds__(BT, 8) void featuresim_kernel(
    const float* __restrict__ x,
    const int* __restrict__ x_lengths,
    const float* __restrict__ fimp,
    float* __restrict__ out)
{
    const int tid = threadIdx.x;
    const int b   = blockIdx.x >> 6;            // 64 row-groups per batch
    const int i0  = (blockIdx.x & 63) * TI;
    const int len = x_lengths[b];

    float fi[NF];
    #pragma unroll
    for (int k = 0; k < NF; ++k) fi[k] = fimp[k];

    const int j0 = tid;
    float fj[NF];
    {
        const float4* p = reinterpret_cast<const float4*>(
            x + (size_t)(b * NN + j0) * DD);
        float4 a = p[0], c = p[1], d = p[2];
        fj[0] = a.x; fj[1] = a.y; fj[2]  = a.z; fj[3] = a.w;
        fj[4] = c.x; fj[5] = c.y; fj[6]  = c.z; fj[7] = c.w;
        fj[8] = d.x; fj[9] = d.y; fj[10] = d.z;
    }
    const bool valid = j0 < len;

    __shared__ float partials[TI][BT];
    __shared__ float totals[TI];

    float e[TI];

    #pragma unroll
    for (int r = 0; r < TI; ++r) {
        const float* qp = x + (size_t)(b * NN + i0 + r) * DD;
        float q[NF];
        #pragma unroll
        for (int k = 0; k < NF; ++k) q[k] = qp[k];

        float s = 0.0f;
        #pragma unroll
        for (int k = 0; k < NF; ++k) {
            float d = q[k] - fj[k];
            s = fmaf(-fabsf(d), fi[k], s);
        }
        float val = (s > -1.0f) ? s : 0.0f;
        float ev  = valid ? __expf(val) : 0.0f;
        e[r] = ev;
        partials[r][tid] = ev;
    }
    __syncthreads();

    const int lane = tid & 63;
    const int wid  = tid >> 6;
    {
        float s = 0.0f;
        #pragma unroll
        for (int m = 0; m < BT / 64; ++m)
            s += partials[wid][lane + 64 * m];
        #pragma unroll
        for (int off = 32; off >= 1; off >>= 1)
            s += __shfl_xor(s, off, 64);
        if (lane == 0) totals[wid] = s;
    }
    __syncthreads();

    #pragma unroll
    for (int r = 0; r < TI; ++r) {
        const float inv = __builtin_amdgcn_rcpf(totals[r]);
        out[(size_t)(b * NN + i0 + r) * NN + j0] = e[r] * inv;
    }
}

extern "C" void kernel_launch(void* const* d_in, const int* in_sizes, int n_in,
                              void* d_out, int out_size, void* d_ws, size_t ws_size,
                              hipStream_t stream) {
    const float* x    = (const float*)d_in[0];
    const int*   xlen = (const int*)d_in[1];
    const float* fimp = (const float*)d_in[2];
    float*       out  = (float*)d_out;

    const int B = in_sizes[1];                  // 8
    dim3 grid(B * (NN / TI));                   // 512 blocks
    dim3 block(BT);
    // PROBE: two identical, idempotent launches in the timed graph.
    featuresim_kernel<<<grid, block, 0, stream>>>(x, xlen, fimp, out);
    featuresim_kernel<<<grid, block, 0, stream>>>(x, xlen, fimp, out);
}

// Round 7
// 21.890 us; speedup vs baseline: 1.5155x; 1.5155x over previous
//
#include <hip/hip_runtime.h>

#define NN 1024
#define DD 64
#define NF 11
#define NFP 12        // padded q row (48B, 16B-aligned for b128 reads)
#define TI 16
#define BT 1024

// Softmax-without-max is exact here: valid scores are in (-1, 0] and masked
// keys contribute exactly +0.0. len >= 1 guarantees every row-sum > 0.
// Key change vs R5: the block's 16 query rows (704B) are staged to LDS ONCE
// (3 wave-instrs/block) instead of every wave re-loading them from global
// (176 VMEM instrs/wave, ~5.6K VMEM instrs per CU = the dominant exec cost).
// Phase-1 q reads are broadcast ds_read_b128 (48/wave, conflict-free).
__global__ __launch_bounds__(BT, 8) void featuresim_kernel(
    const float* __restrict__ x,
    const int* __restrict__ x_lengths,
    const float* __restrict__ fimp,
    float* __restrict__ out)
{
    const int tid = threadIdx.x;
    const int b   = blockIdx.x >> 6;            // 64 row-groups per batch
    const int i0  = (blockIdx.x & 63) * TI;
    const int len = x_lengths[b];

    // feature_importance: uniform -> SGPRs
    float fi[NF];
    #pragma unroll
    for (int k = 0; k < NF; ++k) fi[k] = fimp[k];

    __shared__ float lds_q[TI][NFP];      // 768 B
    __shared__ float partials[TI][BT];    // 64 KiB
    __shared__ float totals[TI];

    // ---- stage q rows once per block: tid t in [0,176) loads row t/11, feat t%11
    if (tid < TI * NF) {
        const int r = tid / NF;
        const int k = tid - r * NF;
        lds_q[r][k] = x[(size_t)(b * NN + i0 + r) * DD + k];
    }

    // each thread owns ONE key row j = tid; 11 VGPRs of key features
    const int j0 = tid;
    float fj[NF];
    {
        const float4* p = reinterpret_cast<const float4*>(
            x + (size_t)(b * NN + j0) * DD);
        float4 a = p[0], c = p[1], d = p[2];
        fj[0] = a.x; fj[1] = a.y; fj[2]  = a.z; fj[3] = a.w;
        fj[4] = c.x; fj[5] = c.y; fj[6]  = c.z; fj[7] = c.w;
        fj[8] = d.x; fj[9] = d.y; fj[10] = d.z;
    }
    const bool valid = j0 < len;

    __syncthreads();                      // q staged

    float e[TI];                          // statically indexed -> 16 VGPRs

    // ---- phase 1: all 16 rows, q via broadcast ds_read_b128 (3 per row)
    #pragma unroll
    for (int r = 0; r < TI; ++r) {
        const float4* qv = reinterpret_cast<const float4*>(&lds_q[r][0]);
        float4 q0 = qv[0], q1 = qv[1], q2 = qv[2];   // q2.w = pad (unused)
        float q[NF] = { q0.x, q0.y, q0.z, q0.w,
                        q1.x, q1.y, q1.z, q1.w,
                        q2.x, q2.y, q2.z };

        float s = 0.0f;                        // accumulates -attn
        #pragma unroll
        for (int k = 0; k < NF; ++k) {
            float d = q[k] - fj[k];
            s = fmaf(-fabsf(d), fi[k], s);     // -abs() is a VOP3 input mod
        }
        float val = (s > -1.0f) ? s : 0.0f;    // (attn<1) ? -attn : 0
        float ev  = valid ? __expf(val) : 0.0f;
        e[r] = ev;
        partials[r][tid] = ev;
    }
    __syncthreads();

    // ---- phase 2: wave w reduces row w (16 waves, one row each)
    const int lane = tid & 63;
    const int wid  = tid >> 6;
    {
        float s = 0.0f;
        #pragma unroll
        for (int m = 0; m < BT / 64; ++m)
            s += partials[wid][lane + 64 * m];
        #pragma unroll
        for (int off = 32; off >= 1; off >>= 1)
            s += __shfl_xor(s, off, 64);
        if (lane == 0) totals[wid] = s;
    }
    __syncthreads();

    // ---- phase 3: normalize + coalesced dword stores (256B/wave)
    #pragma unroll
    for (int r = 0; r < TI; ++r) {
        const float inv = __builtin_amdgcn_rcpf(totals[r]);
        out[(size_t)(b * NN + i0 + r) * NN + j0] = e[r] * inv;
    }
}

extern "C" void kernel_launch(void* const* d_in, const int* in_sizes, int n_in,
                              void* d_out, int out_size, void* d_ws, size_t ws_size,
                              hipStream_t stream) {
    const float* x    = (const float*)d_in[0];
    const int*   xlen = (const int*)d_in[1];
    const float* fimp = (const float*)d_in[2];
    float*       out  = (float*)d_out;

    const int B = in_sizes[1];                  // 8
    dim3 grid(B * (NN / TI));                   // 512 blocks = 1 resident generation
    dim3 block(BT);
    featuresim_kernel<<<grid, block, 0, stream>>>(x, xlen, fimp, out);
}

// Round 8
// 19.176 us; speedup vs baseline: 1.7299x; 1.1415x over previous
//
#include <hip/hip_runtime.h>

#define NN 1024
#define DD 64
#define NF 11
#define TI 16
#define H  8          // half of TI
#define BT 1024

// Softmax-without-max is exact here: valid scores are in (-1, 0], masked keys
// contribute exactly +0.0, len >= 1 so every row-sum > 0.
//
// Split-half pipeline (vs R5's monolithic phases, which serialized the VALU,
// DS and VMEM pipes):  compute H0 | reduce H0 (waves 0-7, DS) OVERLAPS
// compute H1 (VALU) | store H0 (VMEM) OVERLAPS reduce H1 (waves 8-15, DS) |
// store H1.  Three barriers, wave-uniform divergence only.
__global__ __launch_bounds__(BT, 8) void featuresim_kernel(
    const float* __restrict__ x,
    const int* __restrict__ x_lengths,
    const float* __restrict__ fimp,
    float* __restrict__ out)
{
    const int tid = threadIdx.x;
    const int b   = blockIdx.x >> 6;            // 64 row-groups per batch
    const int i0  = (blockIdx.x & 63) * TI;
    const int len = x_lengths[b];

    // feature_importance: uniform -> SGPRs
    float fi[NF];
    #pragma unroll
    for (int k = 0; k < NF; ++k) fi[k] = fimp[k];

    // each thread owns ONE key row j = tid
    const int j0 = tid;
    float fj[NF];
    {
        const float4* p = reinterpret_cast<const float4*>(
            x + (size_t)(b * NN + j0) * DD);
        float4 a = p[0], c = p[1], d = p[2];
        fj[0] = a.x; fj[1] = a.y; fj[2]  = a.z; fj[3] = a.w;
        fj[4] = c.x; fj[5] = c.y; fj[6]  = c.z; fj[7] = c.w;
        fj[8] = d.x; fj[9] = d.y; fj[10] = d.z;
    }
    const bool valid = j0 < len;

    __shared__ float partials[TI][BT];    // 64 KiB
    __shared__ float totals[TI];

    float e[TI];

    const int lane = tid & 63;
    const int wid  = tid >> 6;

    // ---- compute one row r: e[r] + partials write (q via s_load, uniform addr)
    #define ROW_COMPUTE(r)                                                  \
    {                                                                       \
        const float* qp = x + (size_t)(b * NN + i0 + (r)) * DD;             \
        float s = 0.0f;                                                     \
        _Pragma("unroll")                                                   \
        for (int k = 0; k < NF; ++k) {                                      \
            float d = qp[k] - fj[k];                                        \
            s = fmaf(-fabsf(d), fi[k], s);                                  \
        }                                                                   \
        float val = (s > -1.0f) ? s : 0.0f;                                 \
        float ev  = valid ? __expf(val) : 0.0f;                             \
        e[r] = ev;                                                          \
        partials[r][tid] = ev;                                              \
    }

    // ---- wave-level reduction of one full row (1024 values) via 4x b128
    #define ROW_REDUCE(r)                                                   \
    {                                                                       \
        float s = 0.0f;                                                     \
        _Pragma("unroll")                                                   \
        for (int m = 0; m < 4; ++m) {                                       \
            float4 v4 = *reinterpret_cast<const float4*>(                   \
                &partials[r][lane * 4 + 256 * m]);                          \
            s += (v4.x + v4.y) + (v4.z + v4.w);                             \
        }                                                                   \
        _Pragma("unroll")                                                   \
        for (int off = 32; off >= 1; off >>= 1)                             \
            s += __shfl_xor(s, off, 64);                                    \
        if (lane == 0) totals[r] = s;                                       \
    }

    // ---- phase 1a: rows 0..7
    #pragma unroll
    for (int r = 0; r < H; ++r) ROW_COMPUTE(r)
    __syncthreads();                                    // (1) H0 partials ready

    // ---- waves 0-7: reduce H0 (DS pipe) ... overlaps ...
    if (wid < H) ROW_REDUCE(wid)
    // ---- all waves: compute rows 8..15 (VALU pipe)
    #pragma unroll
    for (int r = H; r < TI; ++r) ROW_COMPUTE(r)
    __syncthreads();                                    // (2) totals[0..7] + H1 partials ready

    // ---- waves 8-15: reduce H1 (DS) ... overlaps H0 stores (VMEM) below
    if (wid >= H) ROW_REDUCE(H + (wid - H))
    #pragma unroll
    for (int r = 0; r < H; ++r) {
        const float inv = __builtin_amdgcn_rcpf(totals[r]);
        out[(size_t)(b * NN + i0 + r) * NN + j0] = e[r] * inv;
    }
    __syncthreads();                                    // (3) totals[8..15] ready

    // ---- stores H1
    #pragma unroll
    for (int r = H; r < TI; ++r) {
        const float inv = __builtin_amdgcn_rcpf(totals[r]);
        out[(size_t)(b * NN + i0 + r) * NN + j0] = e[r] * inv;
    }
}

extern "C" void kernel_launch(void* const* d_in, const int* in_sizes, int n_in,
                              void* d_out, int out_size, void* d_ws, size_t ws_size,
                              hipStream_t stream) {
    const float* x    = (const float*)d_in[0];
    const int*   xlen = (const int*)d_in[1];
    const float* fimp = (const float*)d_in[2];
    float*       out  = (float*)d_out;

    const int B = in_sizes[1];                  // 8
    dim3 grid(B * (NN / TI));                   // 512 blocks = 1 resident generation
    dim3 block(BT);
    featuresim_kernel<<<grid, block, 0, stream>>>(x, xlen, fimp, out);
}